// Round 3
// baseline (496.639 us; speedup 1.0000x reference)
//
#include <hip/hip_runtime.h>
#include <stdint.h>

typedef _Float16 half8 __attribute__((ext_vector_type(8)));   // fp16 MFMA frag (4 VGPRs)
typedef __attribute__((ext_vector_type(4))) float f32x4;      // MFMA accumulator
typedef __attribute__((ext_vector_type(8))) unsigned short us8;

__device__ inline unsigned short f2h(float x) {
  _Float16 h = (_Float16)x;                 // v_cvt_f16_f32, RNE
  return __builtin_bit_cast(unsigned short, h);
}

// ---- async global->LDS, 16B per lane ----
__device__ inline void ld16(const unsigned short* g, unsigned short* l) {
  __builtin_amdgcn_global_load_lds(
      (const __attribute__((address_space(1))) unsigned int*)g,
      (__attribute__((address_space(3))) unsigned int*)l, 16, 0, 0);
}

// ---- V [K x D] fp32 -> VT-chunk [D x Kc] fp16 (per batch, k-chunk) ----
__global__ void k_transpose16(const float* __restrict__ V, unsigned short* __restrict__ VT,
                              int Kn, int Dn, int k0c, int Kc) {
  __shared__ unsigned short t[64][65];
  const int b = blockIdx.z;
  const int k0 = blockIdx.x * 64, d0 = blockIdx.y * 64;
  const int c = threadIdx.x & 63, rr = threadIdx.x >> 6;
  const float* pV = V + (long)b * Kn * Dn;
  unsigned short* pT = VT + (long)b * Dn * Kc;
#pragma unroll
  for (int i = 0; i < 16; ++i) {
    int r = rr + i * 4;
    t[r][c] = f2h(pV[(long)(k0c + k0 + r) * Dn + d0 + c]);
  }
  __syncthreads();
#pragma unroll
  for (int i = 0; i < 16; ++i) {
    int r = rr + i * 4;
    pT[(long)(d0 + r) * Kc + k0 + c] = t[c][r];
  }
}

// ============================================================================
// 256x256-tile GEMM, 8 waves (2M x 4N), BK=32, 4 LDS buffers (128 KiB).
// R2's pipelined 1-barrier K-loop, now with fused staging:
//   MODE 0 (QK^T): A=Q f32, B=K f32 -> on-the-fly f16 cast, reg-staged with
//     write-side LDS XOR swizzle; emits S f32 + column-stats partials.
//   MODE 1 (PV):   A=S f32 + st -> P=exp(S-M)*invL cast f16 (fused pcomp);
//     B=VT f16 via global_load_lds (inverse-swizzled source). ACC: out +=.
// One barrier + lgkm-drain per K-tile; loads for tile t+2 issue early in
// tile t, cvt+ds_write after MFMA_LO (latency hidden under MFMA).
// ============================================================================

#define SBAR() __builtin_amdgcn_s_barrier()
#define SCHED0() __builtin_amdgcn_sched_barrier(0)
#define LGKM0() asm volatile("s_waitcnt lgkmcnt(0)" ::: "memory")

template <int MODE, int ACC>
__launch_bounds__(512, 2)
__global__ void k_gemm(const float* __restrict__ Af,           // M0: Q ; M1: S
                       const float* __restrict__ Bf,           // M0: K rows (chunk base)
                       const unsigned short* __restrict__ Bh,  // M1: VT chunk
                       const float2* __restrict__ st,          // M1: (M, invL) per k
                       float* __restrict__ C, float2* __restrict__ ps,
                       int N, int Kin, long sA, long sB, long sC) {
  __shared__ unsigned short sAb[4][256 * 32];
  __shared__ unsigned short sBb[4][256 * 32];

  const int tid = threadIdx.x;
  const int lane = tid & 63, wave = tid >> 6;
  const int wr = wave >> 2, wc = wave & 3;   // 2 x 4 wave grid; wave owns 128x64
  const int l15 = lane & 15;

  // ---- T1: bijective XCD swizzle (all grids here have nwg % 8 == 0) ----
  const int nx = gridDim.x, ny = gridDim.y;
  int wg = ((int)blockIdx.z * ny + blockIdx.y) * nx + blockIdx.x;
  const int nwg = nx * ny * (int)gridDim.z;
  wg = (wg & 7) * (nwg >> 3) + (wg >> 3);
  const int tn = wg % nx, tm = (wg / nx) % ny, b = wg / (nx * ny);

  const float* pA = Af + b * sA + (long)tm * 256 * Kin;
  const float* pBf = nullptr;
  const unsigned short* pBh = nullptr;
  const float2* stp = nullptr;
  if constexpr (MODE == 0) pBf = Bf + b * sB + (long)tn * 256 * Kin;
  else { pBh = Bh + b * sB + (long)tn * 256 * Kin; stp = st + (long)b * Kin; }
  float* pC = C + b * sC;

  // ---- staging addressing: thread covers rows {rlo, rlo+128}, 8 cols ----
  const int rlo = tid >> 2;
  const int c0 = (tid & 3) * 8;
  const int key = ((rlo >> 1) & 3) << 3;     // XOR swizzle key (row bits 1-2)
  const int cx = c0 ^ key;                   // swizzled LDS col (ds_write path)
  const long arA = (long)rlo * Kin + c0;     // linear f32 source
  const long arA2 = arA + 128L * Kin;
  const long gaB = (long)rlo * Kin + cx;     // M1 B: inverse-swizzled source
  const long ghB = 128L * Kin;

  // ---- fragment ds_read offsets (same XOR on the read side) ----
  const int ksw = ((lane >> 4) * 8) ^ (((l15 >> 1) & 3) << 3);
  const int aoff = (wr * 128 + l15) * 32 + ksw;   // + m*512 per 16-row step
  const int boff = (wc * 64 + l15) * 32 + ksw;    // + n*512 per 16-row step

#define LDA8(q, m) (*(const half8*)&sAb[q][aoff + (m) * 512])
#define LDB8(q, n) (*(const half8*)&sBb[q][boff + (n) * 512])

  float4 La0, La1, La2, La3, Lb0, Lb1, Lb2, Lb3;  // staging regs (M1: Lb*=st)

#define ISSUE(t) do { \
    const long kb_ = (long)(t) * 32; \
    if constexpr (MODE == 1) { \
      ld16(pBh + gaB + kb_, &sBb[(t) & 3][tid * 8]); \
      ld16(pBh + gaB + ghB + kb_, &sBb[(t) & 3][4096 + tid * 8]); \
    } \
    La0 = *(const float4*)(pA + arA + kb_); \
    La1 = *(const float4*)(pA + arA + kb_ + 4); \
    La2 = *(const float4*)(pA + arA2 + kb_); \
    La3 = *(const float4*)(pA + arA2 + kb_ + 4); \
    if constexpr (MODE == 0) { \
      Lb0 = *(const float4*)(pBf + arA + kb_); \
      Lb1 = *(const float4*)(pBf + arA + kb_ + 4); \
      Lb2 = *(const float4*)(pBf + arA2 + kb_); \
      Lb3 = *(const float4*)(pBf + arA2 + kb_ + 4); \
    } else { \
      const float2* sp_ = stp + kb_ + c0; \
      Lb0 = *(const float4*)sp_;       Lb1 = *(const float4*)(sp_ + 2); \
      Lb2 = *(const float4*)(sp_ + 4); Lb3 = *(const float4*)(sp_ + 6); \
    } \
  } while (0)

#define CVTW(q) do { \
    us8 h_; \
    if constexpr (MODE == 0) { \
      h_[0]=f2h(La0.x); h_[1]=f2h(La0.y); h_[2]=f2h(La0.z); h_[3]=f2h(La0.w); \
      h_[4]=f2h(La1.x); h_[5]=f2h(La1.y); h_[6]=f2h(La1.z); h_[7]=f2h(La1.w); \
      *(us8*)&sAb[q][rlo * 32 + cx] = h_; \
      h_[0]=f2h(La2.x); h_[1]=f2h(La2.y); h_[2]=f2h(La2.z); h_[3]=f2h(La2.w); \
      h_[4]=f2h(La3.x); h_[5]=f2h(La3.y); h_[6]=f2h(La3.z); h_[7]=f2h(La3.w); \
      *(us8*)&sAb[q][4096 + rlo * 32 + cx] = h_; \
      h_[0]=f2h(Lb0.x); h_[1]=f2h(Lb0.y); h_[2]=f2h(Lb0.z); h_[3]=f2h(Lb0.w); \
      h_[4]=f2h(Lb1.x); h_[5]=f2h(Lb1.y); h_[6]=f2h(Lb1.z); h_[7]=f2h(Lb1.w); \
      *(us8*)&sBb[q][rlo * 32 + cx] = h_; \
      h_[0]=f2h(Lb2.x); h_[1]=f2h(Lb2.y); h_[2]=f2h(Lb2.z); h_[3]=f2h(Lb2.w); \
      h_[4]=f2h(Lb3.x); h_[5]=f2h(Lb3.y); h_[6]=f2h(Lb3.z); h_[7]=f2h(Lb3.w); \
      *(us8*)&sBb[q][4096 + rlo * 32 + cx] = h_; \
    } else { \
      h_[0]=f2h(__expf(La0.x - Lb0.x) * Lb0.y); \
      h_[1]=f2h(__expf(La0.y - Lb0.z) * Lb0.w); \
      h_[2]=f2h(__expf(La0.z - Lb1.x) * Lb1.y); \
      h_[3]=f2h(__expf(La0.w - Lb1.z) * Lb1.w); \
      h_[4]=f2h(__expf(La1.x - Lb2.x) * Lb2.y); \
      h_[5]=f2h(__expf(La1.y - Lb2.z) * Lb2.w); \
      h_[6]=f2h(__expf(La1.z - Lb3.x) * Lb3.y); \
      h_[7]=f2h(__expf(La1.w - Lb3.z) * Lb3.w); \
      *(us8*)&sAb[q][rlo * 32 + cx] = h_; \
      h_[0]=f2h(__expf(La2.x - Lb0.x) * Lb0.y); \
      h_[1]=f2h(__expf(La2.y - Lb0.z) * Lb0.w); \
      h_[2]=f2h(__expf(La2.z - Lb1.x) * Lb1.y); \
      h_[3]=f2h(__expf(La2.w - Lb1.z) * Lb1.w); \
      h_[4]=f2h(__expf(La3.x - Lb2.x) * Lb2.y); \
      h_[5]=f2h(__expf(La3.y - Lb2.z) * Lb2.w); \
      h_[6]=f2h(__expf(La3.z - Lb3.x) * Lb3.y); \
      h_[7]=f2h(__expf(La3.w - Lb3.z) * Lb3.w); \
      *(us8*)&sAb[q][4096 + rlo * 32 + cx] = h_; \
    } \
  } while (0)

  f32x4 acc[8][4];
#pragma unroll
  for (int i = 0; i < 8; ++i)
#pragma unroll
    for (int j = 0; j < 4; ++j)
#pragma unroll
      for (int r = 0; r < 4; ++r) acc[i][j][r] = 0.f;

  // frags: aL single-buffered (consumed before reload), bC double, aH single
  half8 aL[4], bC[2][4], aH[4];

#define READ_LO(s, q) \
  aL[0] = LDA8(q, 0); aL[1] = LDA8(q, 1); aL[2] = LDA8(q, 2); aL[3] = LDA8(q, 3); \
  bC[s][0] = LDB8(q, 0); bC[s][1] = LDB8(q, 1); bC[s][2] = LDB8(q, 2); bC[s][3] = LDB8(q, 3);

#define READ_HI(q) \
  aH[0] = LDA8(q, 4); aH[1] = LDA8(q, 5); aH[2] = LDA8(q, 6); aH[3] = LDA8(q, 7);

#define MFMA_ROW(m, a, s) \
  acc[m][0] = __builtin_amdgcn_mfma_f32_16x16x32_f16(a, bC[s][0], acc[m][0], 0, 0, 0); \
  acc[m][1] = __builtin_amdgcn_mfma_f32_16x16x32_f16(a, bC[s][1], acc[m][1], 0, 0, 0); \
  acc[m][2] = __builtin_amdgcn_mfma_f32_16x16x32_f16(a, bC[s][2], acc[m][2], 0, 0, 0); \
  acc[m][3] = __builtin_amdgcn_mfma_f32_16x16x32_f16(a, bC[s][3], acc[m][3], 0, 0, 0);

#define MFMA_LO(s) \
  __builtin_amdgcn_s_setprio(1); \
  MFMA_ROW(0, aL[0], s) MFMA_ROW(1, aL[1], s) \
  MFMA_ROW(2, aL[2], s) MFMA_ROW(3, aL[3], s) \
  __builtin_amdgcn_s_setprio(0);

#define MFMA_HI(s) \
  __builtin_amdgcn_s_setprio(1); \
  MFMA_ROW(4, aH[0], s) MFMA_ROW(5, aH[1], s) \
  MFMA_ROW(6, aH[2], s) MFMA_ROW(7, aH[3], s) \
  __builtin_amdgcn_s_setprio(0);

  // Tile t: issue loads(t+2) early; MFMA_LO hides their latency; cvt+ds_write
  // (t+2) after; lgkm-drain (write visibility) + barrier; next tile's LO frags.
  // Buffer t+1 was written at tile t-1 and drained before SBAR(t-1) -> safe.
  // WAR: buffer (t+2)&3 held tile t-2, last read before SBAR(t-2) -> safe.
#define TILE(t, s, sn) \
  ISSUE((t) + 2); SCHED0(); \
  READ_HI((t) & 3); \
  MFMA_LO(s) \
  CVTW(((t) + 2) & 3); \
  SCHED0(); LGKM0(); SBAR(); SCHED0(); \
  READ_LO(sn, ((t) + 1) & 3); \
  MFMA_HI(s)

  const int nt = Kin >> 5;   // K-tiles of 32 (even, >= 4)

  // prologue: stage tiles 0,1
  ISSUE(0); CVTW(0);
  ISSUE(1); CVTW(1);
  LGKM0(); SBAR(); SCHED0();
  READ_LO(0, 0);

  for (int t = 0; t + 3 < nt; t += 2) {
    TILE(t, 0, 1);
    TILE(t + 1, 1, 0);
  }
  // peeled last pair (tiles nt-2, nt-1): all staged & barriered; no syncs left
  {
    READ_HI((nt - 2) & 3);
    MFMA_LO(0)
    READ_LO(1, (nt - 1) & 3);
    MFMA_HI(0)
    READ_HI((nt - 1) & 3);
    MFMA_LO(1)
    MFMA_HI(1)
  }

  // ---- epilogue: C write (C/D layout: col=lane&15, row=(lane>>4)*4+r) ----
  const int crow0 = tm * 256 + wr * 128 + (lane >> 4) * 4;
  const int ccol0 = tn * 256 + wc * 64 + l15;
#pragma unroll
  for (int m = 0; m < 8; ++m)
#pragma unroll
    for (int n = 0; n < 4; ++n)
#pragma unroll
      for (int r = 0; r < 4; ++r) {
        long idx = (long)(crow0 + m * 16 + r) * N + ccol0 + n * 16;
        if constexpr (ACC) pC[idx] += acc[m][n][r];
        else pC[idx] = acc[m][n][r];
      }

  if constexpr (MODE == 0) {
    // per-wave column stats over this wave's 128 rows; 16 slots per (b, col)
#pragma unroll
    for (int n = 0; n < 4; ++n) {
      float mx = -3.0e38f;
#pragma unroll
      for (int m = 0; m < 8; ++m)
#pragma unroll
        for (int r = 0; r < 4; ++r) mx = fmaxf(mx, acc[m][n][r]);
      mx = fmaxf(mx, __shfl_xor(mx, 16, 64));
      mx = fmaxf(mx, __shfl_xor(mx, 32, 64));
      float l = 0.f;
#pragma unroll
      for (int m = 0; m < 8; ++m)
#pragma unroll
        for (int r = 0; r < 4; ++r) l += __expf(acc[m][n][r] - mx);
      l += __shfl_xor(l, 16, 64);
      l += __shfl_xor(l, 32, 64);
      if (lane < 16) {
        int col = tn * 256 + wc * 64 + n * 16 + lane;
        ps[((long)(b * 16 + tm * 2 + wr)) * N + col] = make_float2(mx, l);
      }
    }
  }
}

// ---- combine 16 per-tile partials -> (M_k, 1/L_k) ----
__global__ void k_stats_combine(const float2* __restrict__ ps, float2* __restrict__ st, int Kc) {
  const long i = (long)blockIdx.x * blockDim.x + threadIdx.x;  // over 8*Kc
  const int b = (int)(i / Kc), k = (int)(i % Kc);
  float M = -3.0e38f;
#pragma unroll
  for (int j = 0; j < 16; ++j) M = fmaxf(M, ps[((long)(b * 16 + j)) * Kc + k].x);
  float L = 0.f;
#pragma unroll
  for (int j = 0; j < 16; ++j) {
    float2 v = ps[((long)(b * 16 + j)) * Kc + k];
    L += v.y * __expf(v.x - M);
  }
  st[i] = make_float2(M, 1.0f / L);
}

extern "C" void kernel_launch(void* const* d_in, const int* in_sizes, int n_in,
                              void* d_out, int out_size, void* d_ws, size_t ws_size,
                              hipStream_t stream) {
  const float* Q = (const float*)d_in[0];
  const float* Kp = (const float*)d_in[1];
  const float* V = (const float*)d_in[2];
  float* out = (float*)d_out;

  constexpr int Bb = 8, Qn = 2048, Kn = 2048, Dn = 1024;
  constexpr long QD = (long)Qn * Dn, KD = (long)Kn * Dn;

  // k-chunk size: prefer Kc=1024 (full-GPU gemm1 grid), fallback 512
  long Kc = 1024;
  {
    size_t need = (size_t)Bb * Qn * Kc * 4      // S chunk
                + (size_t)Bb * Dn * Kc * 2      // vt chunk
                + (size_t)Bb * 16 * Kc * 8      // partial stats
                + (size_t)Bb * Kc * 8;          // final stats
    if (need > ws_size) Kc = 512;
  }
  const int nc = Kn / (int)Kc;

  char* w = (char*)d_ws;
  float* S           = (float*)w;          w += (size_t)Bb * Qn * Kc * 4;
  unsigned short* vt = (unsigned short*)w; w += (size_t)Bb * Dn * Kc * 2;
  float2* ps         = (float2*)w;         w += (size_t)Bb * 16 * Kc * 8;
  float2* st         = (float2*)w;

  for (int c = 0; c < nc; ++c) {
    const int k0c = c * (int)Kc;
    k_transpose16<<<dim3((int)Kc / 64, Dn / 64, Bb), 256, 0, stream>>>(
        V, vt, Kn, Dn, k0c, (int)Kc);
    // S[:, :, chunk] = Q @ K_chunk^T  (+ column stats)
    k_gemm<0, 0><<<dim3((int)Kc / 256, Qn / 256, Bb), 512, 0, stream>>>(
        Q, Kp + (long)k0c * Dn, nullptr, nullptr, S, ps,
        (int)Kc, Dn, QD, KD, (long)Qn * Kc);
    k_stats_combine<<<Bb * (int)Kc / 256, 256, 0, stream>>>(ps, st, (int)Kc);
    // out (+)= P_chunk @ V_chunk  (P computed in staging from S + st)
    if (c == 0)
      k_gemm<1, 0><<<dim3(Dn / 256, Qn / 256, Bb), 512, 0, stream>>>(
          S, nullptr, vt, st, out, nullptr, Dn, (int)Kc,
          (long)Qn * Kc, (long)Dn * Kc, QD);
    else
      k_gemm<1, 1><<<dim3(Dn / 256, Qn / 256, Bb), 512, 0, stream>>>(
          S, nullptr, vt, st, out, nullptr, Dn, (int)Kc,
          (long)Qn * Kc, (long)Dn * Kc, QD);
  }
}

// Round 4
// 454.493 us; speedup vs baseline: 1.0927x; 1.0927x over previous
//
#include <hip/hip_runtime.h>
#include <stdint.h>

typedef _Float16 half8 __attribute__((ext_vector_type(8)));   // fp16 MFMA frag (4 VGPRs)
typedef __attribute__((ext_vector_type(4))) float f32x4;      // MFMA accumulator
typedef __attribute__((ext_vector_type(8))) unsigned short us8;

__device__ inline unsigned short f2h(float x) {
  _Float16 h = (_Float16)x;                 // v_cvt_f16_f32, RNE
  return __builtin_bit_cast(unsigned short, h);
}

// ---- async global->LDS, 16B per lane ----
__device__ inline void ld16(const unsigned short* g, unsigned short* l) {
  __builtin_amdgcn_global_load_lds(
      (const __attribute__((address_space(1))) unsigned int*)g,
      (__attribute__((address_space(3))) unsigned int*)l, 16, 0, 0);
}

// ---- fp32 -> fp16 cast, 8 elems/thread (whole tensor) ----
__global__ void k_cast16(const float* __restrict__ in, unsigned short* __restrict__ o, long n8) {
  long i = (long)blockIdx.x * blockDim.x + threadIdx.x;
  if (i >= n8) return;
  float4 a = ((const float4*)in)[i * 2];
  float4 b = ((const float4*)in)[i * 2 + 1];
  us8 h;
  h[0] = f2h(a.x); h[1] = f2h(a.y); h[2] = f2h(a.z); h[3] = f2h(a.w);
  h[4] = f2h(b.x); h[5] = f2h(b.y); h[6] = f2h(b.z); h[7] = f2h(b.w);
  *(us8*)(o + i * 8) = h;
}

// ---- fp32 -> fp16 cast of a K-row chunk per batch ----
__global__ void k_cast16c(const float* __restrict__ in, unsigned short* __restrict__ o,
                          int Kn, int Dn, int k0c, int Kc) {
  const long i = (long)blockIdx.x * blockDim.x + threadIdx.x;
  const long cols8 = (long)Kc * Dn / 8;
  const int b = (int)(i / cols8);
  const long j = i - (long)b * cols8;
  const float* p = in + (long)b * Kn * Dn + (long)k0c * Dn + j * 8;
  float4 a = *(const float4*)p;
  float4 c = *(const float4*)(p + 4);
  us8 h;
  h[0] = f2h(a.x); h[1] = f2h(a.y); h[2] = f2h(a.z); h[3] = f2h(a.w);
  h[4] = f2h(c.x); h[5] = f2h(c.y); h[6] = f2h(c.z); h[7] = f2h(c.w);
  *(us8*)(o + (long)b * Kc * Dn + j * 8) = h;
}

// ---- V [K x D] fp32 -> VT-chunk [D x Kc] fp16 (per batch, k-chunk) ----
__global__ void k_transpose16(const float* __restrict__ V, unsigned short* __restrict__ VT,
                              int Kn, int Dn, int k0c, int Kc) {
  __shared__ unsigned short t[64][65];
  const int b = blockIdx.z;
  const int k0 = blockIdx.x * 64, d0 = blockIdx.y * 64;
  const int c = threadIdx.x & 63, rr = threadIdx.x >> 6;
  const float* pV = V + (long)b * Kn * Dn;
  unsigned short* pT = VT + (long)b * Dn * Kc;
#pragma unroll
  for (int i = 0; i < 16; ++i) {
    int r = rr + i * 4;
    t[r][c] = f2h(pV[(long)(k0c + k0 + r) * Dn + d0 + c]);
  }
  __syncthreads();
#pragma unroll
  for (int i = 0; i < 16; ++i) {
    int r = rr + i * 4;
    pT[(long)(d0 + r) * Kc + k0 + c] = t[c][r];
  }
}

// ============================================================================
// 256x256-tile GEMM, 8 waves (2M x 4N), BK=32, 4 LDS buffers (128 KiB).
// R2's proven pipelined loop: global_load_lds fp16 staging 2 tiles ahead,
// ONE barrier + ONE counted vmcnt(4) per K-tile, fragment double-buffer,
// T1 XCD swizzle, T2 LDS XOR swizzle, T5 setprio.
// C[M,N] (+)= A[M,Kin] * B[N,Kin]^T, fp16 in, fp32 out.
// STATS==1: per-(b, q-tile, row-half) column max/sumexp partials (16 slots).
// ============================================================================

#define SBAR() __builtin_amdgcn_s_barrier()
#define SCHED0() __builtin_amdgcn_sched_barrier(0)
#define VMC(n) do { asm volatile("s_waitcnt vmcnt(" #n ")" ::: "memory"); } while (0)

template <int STATS, int ACC>
__launch_bounds__(512, 2)
__global__ void k_gemm_bt(const unsigned short* __restrict__ A,
                          const unsigned short* __restrict__ B,
                          float* __restrict__ C, float2* __restrict__ ps,
                          int N, int Kin, long sA, long sB, long sC) {
  __shared__ unsigned short sAb[4][256 * 32];
  __shared__ unsigned short sBb[4][256 * 32];

  const int tid = threadIdx.x;
  const int lane = tid & 63, wave = tid >> 6;
  const int wr = wave >> 2, wc = wave & 3;   // 2 x 4 wave grid; wave owns 128x64
  const int l15 = lane & 15;

  // ---- T1: bijective XCD swizzle (all grids here have nwg % 8 == 0) ----
  const int nx = gridDim.x, ny = gridDim.y;
  int wg = ((int)blockIdx.z * ny + blockIdx.y) * nx + blockIdx.x;
  const int nwg = nx * ny * (int)gridDim.z;
  wg = (wg & 7) * (nwg >> 3) + (wg >> 3);
  const int tn = wg % nx, tm = (wg / nx) % ny, b = wg / (nx * ny);

  const unsigned short* pA = A + b * sA + (long)tm * 256 * Kin;
  const unsigned short* pB = B + b * sB + (long)tn * 256 * Kin;
  float* pC = C + b * sC;

  // ---- staging: linear LDS dest, inverse-swizzled global source (T2) ----
  const int rlo = tid >> 2;                                  // dest row 0..127
  const int csw = ((tid & 3) * 8) ^ (((rlo >> 1) & 3) << 3); // src col chunk
  const long ga = (long)rlo * Kin + csw;
  const long gh = (long)128 * Kin;                           // row-half stride

  // ---- fragment ds_read offsets (same XOR on the read side) ----
  const int ksw = ((lane >> 4) * 8) ^ (((l15 >> 1) & 3) << 3);
  const int aoff = (wr * 128 + l15) * 32 + ksw;   // + m*512 per 16-row step
  const int boff = (wc * 64 + l15) * 32 + ksw;    // + n*512 per 16-row step

#define STG(t, q) do { \
    ld16(pA + ga + (long)(t) * 32, &sAb[q][tid * 8]); \
    ld16(pA + ga + gh + (long)(t) * 32, &sAb[q][4096 + tid * 8]); \
    ld16(pB + ga + (long)(t) * 32, &sBb[q][tid * 8]); \
    ld16(pB + ga + gh + (long)(t) * 32, &sBb[q][4096 + tid * 8]); } while (0)

#define LDA8(q, m) (*(const half8*)&sAb[q][aoff + (m) * 512])
#define LDB8(q, n) (*(const half8*)&sBb[q][boff + (n) * 512])

  f32x4 acc[8][4];
#pragma unroll
  for (int i = 0; i < 8; ++i)
#pragma unroll
    for (int j = 0; j < 4; ++j)
#pragma unroll
      for (int r = 0; r < 4; ++r) acc[i][j][r] = 0.f;

  // fragment register sets: aL/bC double-buffered across tiles, aH single
  half8 aL[2][4], bC[2][4], aH[4];

#define READ_LO(s, q) \
  aL[s][0] = LDA8(q, 0); aL[s][1] = LDA8(q, 1); aL[s][2] = LDA8(q, 2); aL[s][3] = LDA8(q, 3); \
  bC[s][0] = LDB8(q, 0); bC[s][1] = LDB8(q, 1); bC[s][2] = LDB8(q, 2); bC[s][3] = LDB8(q, 3);

#define READ_HI(q) \
  aH[0] = LDA8(q, 4); aH[1] = LDA8(q, 5); aH[2] = LDA8(q, 6); aH[3] = LDA8(q, 7);

#define MFMA_ROW(m, a, s) \
  acc[m][0] = __builtin_amdgcn_mfma_f32_16x16x32_f16(a, bC[s][0], acc[m][0], 0, 0, 0); \
  acc[m][1] = __builtin_amdgcn_mfma_f32_16x16x32_f16(a, bC[s][1], acc[m][1], 0, 0, 0); \
  acc[m][2] = __builtin_amdgcn_mfma_f32_16x16x32_f16(a, bC[s][2], acc[m][2], 0, 0, 0); \
  acc[m][3] = __builtin_amdgcn_mfma_f32_16x16x32_f16(a, bC[s][3], acc[m][3], 0, 0, 0);

#define MFMA_LO(s) \
  __builtin_amdgcn_s_setprio(1); \
  MFMA_ROW(0, aL[s][0], s) MFMA_ROW(1, aL[s][1], s) \
  MFMA_ROW(2, aL[s][2], s) MFMA_ROW(3, aL[s][3], s) \
  __builtin_amdgcn_s_setprio(0);

#define MFMA_HI(s) \
  __builtin_amdgcn_s_setprio(1); \
  MFMA_ROW(4, aH[0], s) MFMA_ROW(5, aH[1], s) \
  MFMA_ROW(6, aH[2], s) MFMA_ROW(7, aH[3], s) \
  __builtin_amdgcn_s_setprio(0);

  // Per tile t (set s = t&1): see R2 ledger — 4 loads/tile, 2 tiles in
  // flight, steady-state wait vmcnt(4); one barrier/tile.
#define TILE_MAIN(t, s, sn) \
  READ_HI((t) & 3); \
  STG((t) + 2, ((t) + 2) & 3); \
  MFMA_LO(s) \
  VMC(4); SBAR(); SCHED0(); \
  READ_LO(sn, ((t) + 1) & 3); \
  MFMA_HI(s)

  const int nt = Kin >> 5;   // K-tiles of 32 (even, >= 4)

  STG(0, 0);
  STG(1, 1);
  VMC(4); SBAR(); SCHED0();
  READ_LO(0, 0);

  for (int t = 0; t + 3 < nt; t += 2) {
    TILE_MAIN(t, 0, 1);
    TILE_MAIN(t + 1, 1, 0);
  }
  // peeled last pair (tiles nt-2, nt-1): no staging; drain vmcnt fully
  {
    READ_HI((nt - 2) & 3);
    MFMA_LO(0)
    VMC(0); SBAR(); SCHED0();
    READ_LO(1, (nt - 1) & 3);
    MFMA_HI(0)
    READ_HI((nt - 1) & 3);
    MFMA_LO(1)
    MFMA_HI(1)
  }

  // ---- epilogue: C write (C/D layout: col=lane&15, row=(lane>>4)*4+r) ----
  const int crow0 = tm * 256 + wr * 128 + (lane >> 4) * 4;
  const int ccol0 = tn * 256 + wc * 64 + l15;
#pragma unroll
  for (int m = 0; m < 8; ++m)
#pragma unroll
    for (int n = 0; n < 4; ++n)
#pragma unroll
      for (int r = 0; r < 4; ++r) {
        long idx = (long)(crow0 + m * 16 + r) * N + ccol0 + n * 16;
        if constexpr (ACC) pC[idx] += acc[m][n][r];
        else pC[idx] = acc[m][n][r];
      }

  if constexpr (STATS) {
    // per-wave column stats over this wave's 128 rows; 16 slots per (b, col)
#pragma unroll
    for (int n = 0; n < 4; ++n) {
      float mx = -3.0e38f;
#pragma unroll
      for (int m = 0; m < 8; ++m)
#pragma unroll
        for (int r = 0; r < 4; ++r) mx = fmaxf(mx, acc[m][n][r]);
      mx = fmaxf(mx, __shfl_xor(mx, 16, 64));
      mx = fmaxf(mx, __shfl_xor(mx, 32, 64));
      float l = 0.f;
#pragma unroll
      for (int m = 0; m < 8; ++m)
#pragma unroll
        for (int r = 0; r < 4; ++r) l += __expf(acc[m][n][r] - mx);
      l += __shfl_xor(l, 16, 64);
      l += __shfl_xor(l, 32, 64);
      if (lane < 16) {
        int col = tn * 256 + wc * 64 + n * 16 + lane;
        ps[((long)(b * 16 + tm * 2 + wr)) * N + col] = make_float2(mx, l);
      }
    }
  }
}

// ---- combine 16 per-tile partials -> (M_k, 1/L_k) ----
__global__ void k_stats_combine(const float2* __restrict__ ps, float2* __restrict__ st, int Kc) {
  const long i = (long)blockIdx.x * blockDim.x + threadIdx.x;  // over 8*Kc
  const int b = (int)(i / Kc), k = (int)(i % Kc);
  float M = -3.0e38f;
#pragma unroll
  for (int j = 0; j < 16; ++j) M = fmaxf(M, ps[((long)(b * 16 + j)) * Kc + k].x);
  float L = 0.f;
#pragma unroll
  for (int j = 0; j < 16; ++j) {
    float2 v = ps[((long)(b * 16 + j)) * Kc + k];
    L += v.y * __expf(v.x - M);
  }
  st[i] = make_float2(M, 1.0f / L);
}

// ---- P = exp(S - M_k) * invL_k -> fp16, 8 elems/thread (chunk) ----
__global__ void k_pcomp(const float* __restrict__ S, const float2* __restrict__ st,
                        unsigned short* __restrict__ P, int Kc) {
  const long i = (long)blockIdx.x * blockDim.x + threadIdx.x;
  const int kw = Kc >> 3;              // threads per row
  const long r = i / kw;               // row = b*2048 + q
  const int kb = (int)(i - r * kw) * 8;
  const int b = (int)(r >> 11);
  const float* sp = S + r * Kc + kb;
  float4 s0 = *(const float4*)sp;
  float4 s1 = *(const float4*)(sp + 4);
  const float2* tp = st + (long)b * Kc + kb;
  us8 o;
  float sv[8] = {s0.x, s0.y, s0.z, s0.w, s1.x, s1.y, s1.z, s1.w};
#pragma unroll
  for (int j = 0; j < 8; ++j) {
    float2 t = tp[j];
    o[j] = f2h(__expf(sv[j] - t.x) * t.y);
  }
  *(us8*)(P + r * Kc + kb) = o;
}

extern "C" void kernel_launch(void* const* d_in, const int* in_sizes, int n_in,
                              void* d_out, int out_size, void* d_ws, size_t ws_size,
                              hipStream_t stream) {
  const float* Q = (const float*)d_in[0];
  const float* Kp = (const float*)d_in[1];
  const float* V = (const float*)d_in[2];
  float* out = (float*)d_out;

  constexpr int Bb = 8, Qn = 2048, Kn = 2048, Dn = 1024;
  constexpr long QD = (long)Qn * Dn;

  // ---- tiered k-chunk size (full-GPU grids preferred) ----
  long Kc = 1024;
  for (;;) {
    size_t uKP = (size_t)Bb * Qn * Kc * 2;        // P (>= k16-chunk size)
    size_t need = (size_t)Bb * QD * 2              // q16
                + uKP                              // union(k16-chunk, P)
                + (size_t)Bb * Dn * Kc * 2         // vt chunk
                + (size_t)Bb * Qn * Kc * 4         // S chunk
                + (size_t)Bb * 16 * Kc * 8         // partial stats
                + (size_t)Bb * Kc * 8;             // final stats
    if (need <= ws_size || Kc == 256) break;
    Kc >>= 1;
  }
  const int nc = Kn / (int)Kc;

  char* w = (char*)d_ws;
  unsigned short* q16 = (unsigned short*)w; w += (size_t)Bb * QD * 2;
  unsigned short* kp  = (unsigned short*)w; w += (size_t)Bb * Qn * Kc * 2;  // k16c & P
  unsigned short* vt  = (unsigned short*)w; w += (size_t)Bb * Dn * Kc * 2;
  float* S            = (float*)w;          w += (size_t)Bb * Qn * Kc * 4;
  float2* ps          = (float2*)w;         w += (size_t)Bb * 16 * Kc * 8;
  float2* st          = (float2*)w;

  unsigned short* k16c = kp;   // alias: k16c dead before P is written
  unsigned short* P    = kp;

  // Q -> fp16 once
  k_cast16<<<(int)(Bb * QD / 8 / 256), 256, 0, stream>>>(Q, q16, Bb * QD / 8);

  for (int c = 0; c < nc; ++c) {
    const int k0c = c * (int)Kc;
    // K-chunk -> fp16 ; V-chunk -> VT fp16
    k_cast16c<<<(int)((long)Bb * Kc * Dn / 8 / 256), 256, 0, stream>>>(
        Kp, k16c, Kn, Dn, k0c, (int)Kc);
    k_transpose16<<<dim3((int)Kc / 64, Dn / 64, Bb), 256, 0, stream>>>(
        V, vt, Kn, Dn, k0c, (int)Kc);
    // S[:, :, chunk] = Q @ K_chunk^T  (+ column stats over q)
    k_gemm_bt<1, 0><<<dim3((int)Kc / 256, Qn / 256, Bb), 512, 0, stream>>>(
        q16, k16c, S, ps, (int)Kc, Dn, QD, (long)Kc * Dn, (long)Qn * Kc);
    k_stats_combine<<<Bb * (int)Kc / 256, 256, 0, stream>>>(ps, st, (int)Kc);
    // P = exp(S - M) * invL  (fp16, overwrites k16c slot)
    k_pcomp<<<(int)((long)Bb * Qn * (Kc / 8) / 256), 256, 0, stream>>>(
        S, st, P, (int)Kc);
    // out (+)= P_chunk @ V_chunk
    if (c == 0)
      k_gemm_bt<0, 0><<<dim3(Dn / 256, Qn / 256, Bb), 512, 0, stream>>>(
          P, vt, out, nullptr, Dn, (int)Kc, (long)Qn * Kc, (long)Dn * Kc, QD);
    else
      k_gemm_bt<0, 1><<<dim3(Dn / 256, Qn / 256, Bb), 512, 0, stream>>>(
          P, vt, out, nullptr, Dn, (int)Kc, (long)Qn * Kc, (long)Dn * Kc, QD);
  }
}